// Round 2
// baseline (112.412 us; speedup 1.0000x reference)
//
#include <hip/hip_runtime.h>
#include <cstdint>

#define K_V_C   1.05f
#define G_DIFF  4.0e-4f   // G_MAX - G_MIN

// I_REF rows 1..3 (row 0 is all zeros)
__device__ __constant__ float c_I1[9] = {-0.00015f,-0.00011f,-7e-05f,-3e-05f,0.f,3e-05f,7e-05f,0.00011f,0.00015f};
__device__ __constant__ float c_I2[9] = {-0.0005f,-0.00035f,-0.00022f,-9e-05f,0.f,9e-05f,0.00022f,0.00035f,0.0005f};
__device__ __constant__ float c_I3[9] = {-0.0009f,-0.0006f,-0.00037f,-0.00015f,0.f,0.00015f,0.00037f,0.0006f,0.0009f};

// ---------------------------------------------------------------------------
// Kernel 1: max(|w|, |b|) reduction -> ws[0] (float bits in uint, atomicMax)
// ---------------------------------------------------------------------------
__global__ __launch_bounds__(256) void maxabs_kernel(const float* __restrict__ w,
                                                     const float* __restrict__ b,
                                                     unsigned int* __restrict__ wsmax) {
  const int NW4 = 262144;        // 1024*1024/4
  const int NB4 = 256;           // 1024/4
  float m = 0.f;
  for (int i = blockIdx.x * blockDim.x + threadIdx.x; i < NW4 + NB4;
       i += gridDim.x * blockDim.x) {
    float4 v = (i < NW4) ? ((const float4*)w)[i] : ((const float4*)b)[i - NW4];
    m = fmaxf(m, fmaxf(fmaxf(fabsf(v.x), fabsf(v.y)),
                       fmaxf(fabsf(v.z), fabsf(v.w))));
  }
  for (int o = 32; o > 0; o >>= 1) m = fmaxf(m, __shfl_down(m, o, 64));
  __shared__ float red[4];
  const int lane = threadIdx.x & 63, wv = threadIdx.x >> 6;
  if (lane == 0) red[wv] = m;
  __syncthreads();
  if (threadIdx.x == 0) {
    m = fmaxf(fmaxf(red[0], red[1]), fmaxf(red[2], red[3]));
    atomicMax(wsmax, __float_as_uint(m));
  }
}

// ---------------------------------------------------------------------------
// Kernel 2: fused memristor crossbar product.
//   grid = (16 m-tiles of 64, 33 j-groups), block = 256.
//   Per 16-j sub-chunk: stage U[b][jl] = {0, U1, U2, U3} (float4) in LDS,
//   XOR-swizzled (jl ^ (b>>3)&7) so both staging writes and inner reads are
//   bank-conflict-free. Thread owns 4 m x 8 b accumulators.
// ---------------------------------------------------------------------------
__global__ __launch_bounds__(256) void memristor_kernel(
    const float* __restrict__ x, const float* __restrict__ w,
    const float* __restrict__ bias, const unsigned int* __restrict__ wsmax,
    float* __restrict__ out) {
  __shared__ float4 U[2048];          // [b:128][jl:16] float4, jl swizzled
  __shared__ float4 T0s[8], TDs[8];   // interp tables per segment, levels 1..3

  const int tid = threadIdx.x;
  if (tid < 8) {
    T0s[tid] = make_float4(c_I1[tid], c_I2[tid], c_I3[tid], 0.f);
    TDs[tid] = make_float4(c_I1[tid+1] - c_I1[tid],
                           c_I2[tid+1] - c_I2[tid],
                           c_I3[tid+1] - c_I3[tid], 0.f);
  }

  const float maxw  = __uint_as_float(*wsmax);
  const float kG    = G_DIFF / maxw;
  const float scale = maxw * (1.0f / (K_V_C * G_DIFF));   // 1/(K_V * k_G)

  const int mq  = tid & 15;          // m-quad lane
  const int bg  = tid >> 4;          // b-group (8 batches each)
  const int m0  = blockIdx.x * 64 + mq * 4;
  const int swz = bg & 7;

  float acc[4][8];
  #pragma unroll
  for (int a = 0; a < 4; ++a)
    #pragma unroll
    for (int c = 0; c < 8; ++c) acc[a][c] = 0.f;

  for (int sc = blockIdx.y; sc < 65; sc += 33) {
    const int j0 = sc * 16;
    const int nj = min(16, 1025 - j0);
    __syncthreads();                       // LDS reuse across sub-chunks
    // ---- stage U for this sub-chunk ----
    #pragma unroll
    for (int k = 0; k < 8; ++k) {
      const int e  = k * 256 + tid;
      const int jl = e & 15, b = e >> 4;
      const int jg = j0 + jl;
      if (jg <= 1024) {
        const float v  = (jg < 1024) ? K_V_C * x[b * 1024 + jg] : K_V_C;
        const float sf = v * 3.3333333333333335f + 4.0f;   // (v+1.2)/0.3
        float fs = floorf(sf);
        fs = fminf(fmaxf(fs, 0.f), 7.f);
        const int   seg = (int)fs;
        const float fr  = fminf(fmaxf(sf - fs, 0.f), 1.f);
        const float4 y0 = T0s[seg], dy = TDs[seg];
        float4 u;
        u.x = 0.f;
        u.y = fmaf(fr, dy.x, y0.x);
        u.z = fmaf(fr, dy.y, y0.y);
        u.w = fmaf(fr, dy.z, y0.z);
        U[b * 16 + (jl ^ ((b >> 3) & 7))] = u;
      }
    }
    __syncthreads();
    // ---- accumulate over this sub-chunk's j values ----
    for (int jl = 0; jl < nj; ++jl) {
      const int jg = j0 + jl;
      const float4 wv = (jg < 1024) ? *(const float4*)(w + jg * 1024 + m0)
                                    : *(const float4*)(bias + m0);
      const float warr[4] = {wv.x, wv.y, wv.z, wv.w};
      float c1[4], c2[4], c3[4];
      #pragma unroll
      for (int mi = 0; mi < 4; ++mi) {
        const float g   = kG * warr[mi];
        const float ga  = fabsf(g);
        const float sgn = (g > 0.f) ? 1.f : ((g < 0.f) ? -1.f : 0.f);
        const int   idx = (ga >= 3e-4f) ? 2 : ((ga >= 1e-4f) ? 1 : 0);
        const float g0   = (idx == 0) ? 0.f : ((idx == 1) ? 1e-4f : 3e-4f);
        const float invd = (idx == 0) ? 1e4f : 5e3f;
        const float t    = (ga - g0) * invd;
        const float clo = sgn * (1.f - t), chi = sgn * t;
        c1[mi] = (idx == 0) ? chi : ((idx == 1) ? clo : 0.f);
        c2[mi] = (idx == 1) ? chi : ((idx == 2) ? clo : 0.f);
        c3[mi] = (idx == 2) ? chi : 0.f;
      }
      const int base = bg * 128 + (jl ^ swz);
      #pragma unroll
      for (int bb = 0; bb < 8; ++bb) {
        const float4 u = U[base + bb * 16];
        #pragma unroll
        for (int mi = 0; mi < 4; ++mi)
          acc[mi][bb] = fmaf(c1[mi], u.y,
                        fmaf(c2[mi], u.z,
                        fmaf(c3[mi], u.w, acc[mi][bb])));
      }
    }
  }

  // ---- epilogue: scaled atomic accumulation into y ----
  #pragma unroll
  for (int bb = 0; bb < 8; ++bb) {
    const int b = bg * 8 + bb;
    #pragma unroll
    for (int mi = 0; mi < 4; ++mi)
      atomicAdd(&out[b * 1024 + m0 + mi], acc[mi][bb] * scale);
  }
}

// ---------------------------------------------------------------------------
extern "C" void kernel_launch(void* const* d_in, const int* in_sizes, int n_in,
                              void* d_out, int out_size, void* d_ws, size_t ws_size,
                              hipStream_t stream) {
  const float* x = (const float*)d_in[0];   // (128, 1024)
  const float* w = (const float*)d_in[1];   // (1024, 1024)
  const float* b = (const float*)d_in[2];   // (1024,)
  float* out = (float*)d_out;               // (128, 1024) fp32
  unsigned int* wsmax = (unsigned int*)d_ws;

  hipMemsetAsync(wsmax, 0, 4, stream);
  hipMemsetAsync(out, 0, (size_t)out_size * sizeof(float), stream);

  maxabs_kernel<<<256, 256, 0, stream>>>(w, b, wsmax);

  dim3 grid(16, 33);
  memristor_kernel<<<grid, 256, 0, stream>>>(x, w, b, wsmax, out);
}

// Round 4
// 54.947 us; speedup vs baseline: 2.0458x; 2.0458x over previous
//
#include <hip/hip_runtime.h>
#include <cstdint>

#define K_V_C   1.05f
#define G_DIFF  4.0e-4f   // G_MAX - G_MIN

// I_REF rows 1..3 (row 0 is all zeros)
__device__ __constant__ float c_I1[9] = {-0.00015f,-0.00011f,-7e-05f,-3e-05f,0.f,3e-05f,7e-05f,0.00011f,0.00015f};
__device__ __constant__ float c_I2[9] = {-0.0005f,-0.00035f,-0.00022f,-9e-05f,0.f,9e-05f,0.00022f,0.00035f,0.0005f};
__device__ __constant__ float c_I3[9] = {-0.0009f,-0.0006f,-0.00037f,-0.00015f,0.f,0.00015f,0.00037f,0.0006f,0.0009f};

// ---------------------------------------------------------------------------
// Kernel 1: max(|w|, |b|) reduction -> ws[0] (float bits in uint, atomicMax)
// ---------------------------------------------------------------------------
__global__ __launch_bounds__(256) void maxabs_kernel(const float* __restrict__ w,
                                                     const float* __restrict__ b,
                                                     unsigned int* __restrict__ wsmax) {
  const int NW4 = 262144;        // 1024*1024/4
  const int NB4 = 256;           // 1024/4
  float m = 0.f;
  for (int i = blockIdx.x * blockDim.x + threadIdx.x; i < NW4 + NB4;
       i += gridDim.x * blockDim.x) {
    float4 v = (i < NW4) ? ((const float4*)w)[i] : ((const float4*)b)[i - NW4];
    m = fmaxf(m, fmaxf(fmaxf(fabsf(v.x), fabsf(v.y)),
                       fmaxf(fabsf(v.z), fabsf(v.w))));
  }
  for (int o = 32; o > 0; o >>= 1) m = fmaxf(m, __shfl_down(m, o, 64));
  __shared__ float red[4];
  const int lane = threadIdx.x & 63, wv = threadIdx.x >> 6;
  if (lane == 0) red[wv] = m;
  __syncthreads();
  if (threadIdx.x == 0) {
    m = fmaxf(fmaxf(red[0], red[1]), fmaxf(red[2], red[3]));
    atomicMax(wsmax, __float_as_uint(m));
  }
}

// ---------------------------------------------------------------------------
// Kernel 2: fused memristor crossbar product.
//   grid = (16 m-tiles of 64, 16 j-chunks), block = 256.
//   PARTIAL=true : block writes unscaled partial tile to ws (no atomics).
//   PARTIAL=false: legacy atomicAdd epilogue (fallback when ws is tiny).
// ---------------------------------------------------------------------------
template <bool PARTIAL>
__global__ __launch_bounds__(256) void memristor_kernel(
    const float* __restrict__ x, const float* __restrict__ w,
    const float* __restrict__ bias, const unsigned int* __restrict__ wsmax,
    float* __restrict__ outp) {
  __shared__ float4 U[2048];          // [b:128][jl:16] float4, jl swizzled
  __shared__ float4 T0s[8], TDs[8];   // interp tables per segment, levels 1..3

  const int tid = threadIdx.x;
  if (tid < 8) {
    T0s[tid] = make_float4(c_I1[tid], c_I2[tid], c_I3[tid], 0.f);
    TDs[tid] = make_float4(c_I1[tid+1] - c_I1[tid],
                           c_I2[tid+1] - c_I2[tid],
                           c_I3[tid+1] - c_I3[tid], 0.f);
  }

  const float maxw  = __uint_as_float(*wsmax);
  const float kG    = G_DIFF / maxw;
  const float scale = maxw * (1.0f / (K_V_C * G_DIFF));   // 1/(K_V * k_G)

  const int mq  = tid & 15;          // m-quad lane
  const int bg  = tid >> 4;          // b-group (8 batches each)
  const int m0  = blockIdx.x * 64 + mq * 4;
  const int swz = bg & 7;

  float acc[4][8];
  #pragma unroll
  for (int a = 0; a < 4; ++a)
    #pragma unroll
    for (int c = 0; c < 8; ++c) acc[a][c] = 0.f;

  // 65 sub-chunks of 16 j; j-chunk jc = blockIdx.y handles sc = jc, jc+16, ...
  for (int sc = blockIdx.y; sc < 65; sc += 16) {
    const int j0 = sc * 16;
    const int nj = min(16, 1025 - j0);
    __syncthreads();                       // LDS reuse across sub-chunks
    // ---- stage U for this sub-chunk ----
    #pragma unroll
    for (int k = 0; k < 8; ++k) {
      const int e  = k * 256 + tid;
      const int jl = e & 15, b = e >> 4;
      const int jg = j0 + jl;
      if (jg <= 1024) {
        const float v  = (jg < 1024) ? K_V_C * x[b * 1024 + jg] : K_V_C;
        const float sf = v * 3.3333333333333335f + 4.0f;   // (v+1.2)/0.3
        float fs = floorf(sf);
        fs = fminf(fmaxf(fs, 0.f), 7.f);
        const int   seg = (int)fs;
        const float fr  = fminf(fmaxf(sf - fs, 0.f), 1.f);
        const float4 y0 = T0s[seg], dy = TDs[seg];
        float4 u;
        u.x = 0.f;
        u.y = fmaf(fr, dy.x, y0.x);
        u.z = fmaf(fr, dy.y, y0.y);
        u.w = fmaf(fr, dy.z, y0.z);
        U[b * 16 + (jl ^ ((b >> 3) & 7))] = u;
      }
    }
    __syncthreads();
    // ---- accumulate over this sub-chunk's j values ----
    for (int jl = 0; jl < nj; ++jl) {
      const int jg = j0 + jl;
      const float4 wv = (jg < 1024) ? *(const float4*)(w + jg * 1024 + m0)
                                    : *(const float4*)(bias + m0);
      const float warr[4] = {wv.x, wv.y, wv.z, wv.w};
      float c1[4], c2[4], c3[4];
      #pragma unroll
      for (int mi = 0; mi < 4; ++mi) {
        const float g   = kG * warr[mi];
        const float ga  = fabsf(g);
        const float sgn = (g > 0.f) ? 1.f : ((g < 0.f) ? -1.f : 0.f);
        const int   idx = (ga >= 3e-4f) ? 2 : ((ga >= 1e-4f) ? 1 : 0);
        const float g0   = (idx == 0) ? 0.f : ((idx == 1) ? 1e-4f : 3e-4f);
        const float invd = (idx == 0) ? 1e4f : 5e3f;
        const float t    = (ga - g0) * invd;
        const float clo = sgn * (1.f - t), chi = sgn * t;
        c1[mi] = (idx == 0) ? chi : ((idx == 1) ? clo : 0.f);
        c2[mi] = (idx == 1) ? chi : ((idx == 2) ? clo : 0.f);
        c3[mi] = (idx == 2) ? chi : 0.f;
      }
      const int base = bg * 128 + (jl ^ swz);
      #pragma unroll
      for (int bb = 0; bb < 8; ++bb) {
        const float4 u = U[base + bb * 16];
        #pragma unroll
        for (int mi = 0; mi < 4; ++mi)
          acc[mi][bb] = fmaf(c1[mi], u.y,
                        fmaf(c2[mi], u.z,
                        fmaf(c3[mi], u.w, acc[mi][bb])));
      }
    }
  }

  if (PARTIAL) {
    // ---- epilogue: plain float4 stores of the unscaled partial tile ----
    float* pp = outp + (size_t)blockIdx.y * 131072;   // [128][1024] slab
    #pragma unroll
    for (int bb = 0; bb < 8; ++bb) {
      const int b = bg * 8 + bb;
      *(float4*)(pp + b * 1024 + m0) =
          make_float4(acc[0][bb], acc[1][bb], acc[2][bb], acc[3][bb]);
    }
  } else {
    // ---- fallback: scaled atomic accumulation into y ----
    #pragma unroll
    for (int bb = 0; bb < 8; ++bb) {
      const int b = bg * 8 + bb;
      #pragma unroll
      for (int mi = 0; mi < 4; ++mi)
        atomicAdd(&outp[b * 1024 + m0 + mi], acc[mi][bb] * scale);
    }
  }
}

// ---------------------------------------------------------------------------
// Kernel 3: reduce 16 partial slabs + apply scale. Fully overwrites out.
//   grid = 128 blocks x 256 threads, one float4 per thread.
// ---------------------------------------------------------------------------
__global__ __launch_bounds__(256) void reduce_kernel(
    const float* __restrict__ partial, const unsigned int* __restrict__ wsmax,
    float* __restrict__ out) {
  const int i = blockIdx.x * 256 + threadIdx.x;       // f4 index, 32768 total
  const float maxw  = __uint_as_float(*wsmax);
  const float scale = maxw * (1.0f / (K_V_C * G_DIFF));
  const float4* p = (const float4*)partial;
  float sx = 0.f, sy = 0.f, sz = 0.f, sw = 0.f;
  #pragma unroll
  for (int jc = 0; jc < 16; ++jc) {
    const float4 v = p[jc * 32768 + i];
    sx += v.x; sy += v.y; sz += v.z; sw += v.w;
  }
  ((float4*)out)[i] = make_float4(sx * scale, sy * scale, sz * scale, sw * scale);
}

// ---------------------------------------------------------------------------
extern "C" void kernel_launch(void* const* d_in, const int* in_sizes, int n_in,
                              void* d_out, int out_size, void* d_ws, size_t ws_size,
                              hipStream_t stream) {
  const float* x = (const float*)d_in[0];   // (128, 1024)
  const float* w = (const float*)d_in[1];   // (1024, 1024)
  const float* b = (const float*)d_in[2];   // (1024,)
  float* out = (float*)d_out;               // (128, 1024) fp32
  unsigned int* wsmax = (unsigned int*)d_ws;
  float* partial = (float*)((char*)d_ws + 256);

  const size_t need = 256 + (size_t)16 * 131072 * sizeof(float);  // 8.39 MB

  hipMemsetAsync(wsmax, 0, 4, stream);
  maxabs_kernel<<<256, 256, 0, stream>>>(w, b, wsmax);

  if (ws_size >= need) {
    dim3 grid(16, 16);
    memristor_kernel<true><<<grid, 256, 0, stream>>>(x, w, b, wsmax, partial);
    reduce_kernel<<<128, 256, 0, stream>>>(partial, wsmax, out);
  } else {
    hipMemsetAsync(out, 0, (size_t)out_size * sizeof(float), stream);
    dim3 grid(16, 16);
    memristor_kernel<false><<<grid, 256, 0, stream>>>(x, w, b, wsmax, out);
  }
}

// Round 5
// 48.244 us; speedup vs baseline: 2.3301x; 1.1389x over previous
//
#include <hip/hip_runtime.h>
#include <cstdint>

#define K_V_C   1.05f
#define G_DIFF  4.0e-4f   // G_MAX - G_MIN

// I_REF rows 1..3 (row 0 is all zeros)
__device__ __constant__ float c_I1[9] = {-0.00015f,-0.00011f,-7e-05f,-3e-05f,0.f,3e-05f,7e-05f,0.00011f,0.00015f};
__device__ __constant__ float c_I2[9] = {-0.0005f,-0.00035f,-0.00022f,-9e-05f,0.f,9e-05f,0.00022f,0.00035f,0.0005f};
__device__ __constant__ float c_I3[9] = {-0.0009f,-0.0006f,-0.00037f,-0.00015f,0.f,0.00015f,0.00037f,0.0006f,0.0009f};

// ---------------------------------------------------------------------------
// Kernel 1: max(|w|, |b|) reduction -> ws[0] (float bits in uint, atomicMax)
// ---------------------------------------------------------------------------
__global__ __launch_bounds__(256) void maxabs_kernel(const float* __restrict__ w,
                                                     const float* __restrict__ b,
                                                     unsigned int* __restrict__ wsmax) {
  const int NW4 = 262144;        // 1024*1024/4
  const int NB4 = 256;           // 1024/4
  float m = 0.f;
  for (int i = blockIdx.x * blockDim.x + threadIdx.x; i < NW4 + NB4;
       i += gridDim.x * blockDim.x) {
    float4 v = (i < NW4) ? ((const float4*)w)[i] : ((const float4*)b)[i - NW4];
    m = fmaxf(m, fmaxf(fmaxf(fabsf(v.x), fabsf(v.y)),
                       fmaxf(fabsf(v.z), fabsf(v.w))));
  }
  for (int o = 32; o > 0; o >>= 1) m = fmaxf(m, __shfl_down(m, o, 64));
  __shared__ float red[4];
  const int lane = threadIdx.x & 63, wv = threadIdx.x >> 6;
  if (lane == 0) red[wv] = m;
  __syncthreads();
  if (threadIdx.x == 0) {
    m = fmaxf(fmaxf(red[0], red[1]), fmaxf(red[2], red[3]));
    atomicMax(wsmax, __float_as_uint(m));
  }
}

// ---------------------------------------------------------------------------
// Kernel 2: fused memristor crossbar product.
//   grid = (16 m-tiles of 64, JCHUNKS j-chunks), block = 256 (16 mq x 16 bg).
//   Per 16-j sub-chunk:
//     stage U[b:128][jl:16] (float4 {0,U1,U2,U3}, XOR-swizzled) and
//     coeff tiles C1/C2/C3[jl:16][mq:16] (float4 over 4 m) in LDS, then a
//     fully-unrolled pure LDS+FMA inner loop (no global loads, no coeff math).
//   PARTIAL=true : block writes unscaled partial tile to ws slab blockIdx.y.
//   PARTIAL=false: atomicAdd epilogue fallback (tiny ws).
// ---------------------------------------------------------------------------
template <int JCHUNKS, bool PARTIAL>
__global__ __launch_bounds__(256, 2) void memristor_kernel(
    const float* __restrict__ x, const float* __restrict__ w,
    const float* __restrict__ bias, const unsigned int* __restrict__ wsmax,
    float* __restrict__ outp) {
  __shared__ float4 U[2048];                    // 32 KB
  __shared__ float4 C1[256], C2[256], C3[256];  // 12 KB
  __shared__ float4 T0s[8], TDs[8];

  const int tid = threadIdx.x;
  if (tid < 8) {
    T0s[tid] = make_float4(c_I1[tid], c_I2[tid], c_I3[tid], 0.f);
    TDs[tid] = make_float4(c_I1[tid+1] - c_I1[tid],
                           c_I2[tid+1] - c_I2[tid],
                           c_I3[tid+1] - c_I3[tid], 0.f);
  }

  const float maxw  = __uint_as_float(*wsmax);
  const float kG    = G_DIFF / maxw;
  const float scale = maxw * (1.0f / (K_V_C * G_DIFF));   // 1/(K_V * k_G)

  const int mq  = tid & 15;          // m-quad lane
  const int bg  = tid >> 4;          // b-group (8 batches each)
  const int m0  = blockIdx.x * 64 + mq * 4;
  const int swz = bg & 7;

  float acc[4][8];
  #pragma unroll
  for (int a = 0; a < 4; ++a)
    #pragma unroll
    for (int c = 0; c < 8; ++c) acc[a][c] = 0.f;

  // 65 sub-chunks of 16 j; j-chunk blockIdx.y handles sc = y, y+JCHUNKS, ...
  for (int sc = blockIdx.y; sc < 65; sc += JCHUNKS) {
    const int j0 = sc * 16;
    __syncthreads();                       // LDS reuse across sub-chunks
    // ---- stage U for this sub-chunk ----
    #pragma unroll
    for (int k = 0; k < 8; ++k) {
      const int e  = k * 256 + tid;
      const int jl = e & 15, b = e >> 4;
      const int jg = j0 + jl;
      if (jg <= 1024) {
        const float v  = (jg < 1024) ? K_V_C * x[b * 1024 + jg] : K_V_C;
        const float sf = v * 3.3333333333333335f + 4.0f;   // (v+1.2)/0.3
        float fs = floorf(sf);
        fs = fminf(fmaxf(fs, 0.f), 7.f);
        const int   seg = (int)fs;
        const float fr  = fminf(fmaxf(sf - fs, 0.f), 1.f);
        const float4 y0 = T0s[seg], dy = TDs[seg];
        float4 u;
        u.x = 0.f;
        u.y = fmaf(fr, dy.x, y0.x);
        u.z = fmaf(fr, dy.y, y0.y);
        u.w = fmaf(fr, dy.z, y0.z);
        U[b * 16 + (jl ^ ((b >> 3) & 7))] = u;
      }
    }
    // ---- stage coefficient tiles: thread (jl=tid>>4, mqc=tid&15) ----
    {
      const int jl  = tid >> 4;
      const int mqc = tid & 15;
      const int jg  = j0 + jl;
      float4 wv = make_float4(0.f, 0.f, 0.f, 0.f);
      if (jg < 1024)        wv = *(const float4*)(w + jg * 1024 + blockIdx.x * 64 + mqc * 4);
      else if (jg == 1024)  wv = *(const float4*)(bias + blockIdx.x * 64 + mqc * 4);
      float4 c1v, c2v, c3v;
      float* c1p = &c1v.x; float* c2p = &c2v.x; float* c3p = &c3v.x;
      const float warr[4] = {wv.x, wv.y, wv.z, wv.w};
      #pragma unroll
      for (int mi = 0; mi < 4; ++mi) {
        const float g   = kG * warr[mi];
        const float ga  = fabsf(g);
        const float sgn = (g > 0.f) ? 1.f : ((g < 0.f) ? -1.f : 0.f);
        const int   idx = (ga >= 3e-4f) ? 2 : ((ga >= 1e-4f) ? 1 : 0);
        const float g0   = (idx == 0) ? 0.f : ((idx == 1) ? 1e-4f : 3e-4f);
        const float invd = (idx == 0) ? 1e4f : 5e3f;
        const float t    = (ga - g0) * invd;
        const float clo = sgn * (1.f - t), chi = sgn * t;
        c1p[mi] = (idx == 0) ? chi : ((idx == 1) ? clo : 0.f);
        c2p[mi] = (idx == 1) ? chi : ((idx == 2) ? clo : 0.f);
        c3p[mi] = (idx == 2) ? chi : 0.f;
      }
      C1[jl * 16 + mqc] = c1v;
      C2[jl * 16 + mqc] = c2v;
      C3[jl * 16 + mqc] = c3v;
    }
    __syncthreads();
    // ---- pure LDS+FMA accumulation ----
    if (j0 + 16 <= 1025) {                 // full sub-chunk: unroll all 16
      #pragma unroll
      for (int jl = 0; jl < 16; ++jl) {
        const float4 c1 = C1[jl * 16 + mq];
        const float4 c2 = C2[jl * 16 + mq];
        const float4 c3 = C3[jl * 16 + mq];
        const int base = bg * 128 + (jl ^ swz);
        #pragma unroll
        for (int bb = 0; bb < 8; ++bb) {
          const float4 u = U[base + bb * 16];
          acc[0][bb] = fmaf(c1.x, u.y, fmaf(c2.x, u.z, fmaf(c3.x, u.w, acc[0][bb])));
          acc[1][bb] = fmaf(c1.y, u.y, fmaf(c2.y, u.z, fmaf(c3.y, u.w, acc[1][bb])));
          acc[2][bb] = fmaf(c1.z, u.y, fmaf(c2.z, u.z, fmaf(c3.z, u.w, acc[2][bb])));
          acc[3][bb] = fmaf(c1.w, u.y, fmaf(c2.w, u.z, fmaf(c3.w, u.w, acc[3][bb])));
        }
      }
    } else {                               // tail sub-chunk (sc=64, nj=1)
      const int nj = 1025 - j0;
      for (int jl = 0; jl < nj; ++jl) {
        const float4 c1 = C1[jl * 16 + mq];
        const float4 c2 = C2[jl * 16 + mq];
        const float4 c3 = C3[jl * 16 + mq];
        const int base = bg * 128 + (jl ^ swz);
        #pragma unroll
        for (int bb = 0; bb < 8; ++bb) {
          const float4 u = U[base + bb * 16];
          acc[0][bb] = fmaf(c1.x, u.y, fmaf(c2.x, u.z, fmaf(c3.x, u.w, acc[0][bb])));
          acc[1][bb] = fmaf(c1.y, u.y, fmaf(c2.y, u.z, fmaf(c3.y, u.w, acc[1][bb])));
          acc[2][bb] = fmaf(c1.z, u.y, fmaf(c2.z, u.z, fmaf(c3.z, u.w, acc[2][bb])));
          acc[3][bb] = fmaf(c1.w, u.y, fmaf(c2.w, u.z, fmaf(c3.w, u.w, acc[3][bb])));
        }
      }
    }
  }

  if (PARTIAL) {
    // ---- epilogue: plain float4 stores of the unscaled partial tile ----
    float* pp = outp + (size_t)blockIdx.y * 131072;   // [128][1024] slab
    #pragma unroll
    for (int bb = 0; bb < 8; ++bb) {
      const int b = bg * 8 + bb;
      *(float4*)(pp + b * 1024 + m0) =
          make_float4(acc[0][bb], acc[1][bb], acc[2][bb], acc[3][bb]);
    }
  } else {
    // ---- fallback: scaled atomic accumulation into y ----
    #pragma unroll
    for (int bb = 0; bb < 8; ++bb) {
      const int b = bg * 8 + bb;
      #pragma unroll
      for (int mi = 0; mi < 4; ++mi)
        atomicAdd(&outp[b * 1024 + m0 + mi], acc[mi][bb] * scale);
    }
  }
}

// ---------------------------------------------------------------------------
// Kernel 3: reduce JCHUNKS partial slabs + apply scale. Overwrites out fully.
//   grid = 128 blocks x 256 threads, one float4 per thread.
// ---------------------------------------------------------------------------
template <int JCHUNKS>
__global__ __launch_bounds__(256) void reduce_kernel(
    const float* __restrict__ partial, const unsigned int* __restrict__ wsmax,
    float* __restrict__ out) {
  const int i = blockIdx.x * 256 + threadIdx.x;       // f4 index, 32768 total
  const float maxw  = __uint_as_float(*wsmax);
  const float scale = maxw * (1.0f / (K_V_C * G_DIFF));
  const float4* p = (const float4*)partial;
  float sx = 0.f, sy = 0.f, sz = 0.f, sw = 0.f;
  #pragma unroll
  for (int jc = 0; jc < JCHUNKS; ++jc) {
    const float4 v = p[jc * 32768 + i];
    sx += v.x; sy += v.y; sz += v.z; sw += v.w;
  }
  ((float4*)out)[i] = make_float4(sx * scale, sy * scale, sz * scale, sw * scale);
}

// ---------------------------------------------------------------------------
extern "C" void kernel_launch(void* const* d_in, const int* in_sizes, int n_in,
                              void* d_out, int out_size, void* d_ws, size_t ws_size,
                              hipStream_t stream) {
  const float* x = (const float*)d_in[0];   // (128, 1024)
  const float* w = (const float*)d_in[1];   // (1024, 1024)
  const float* b = (const float*)d_in[2];   // (1024,)
  float* out = (float*)d_out;               // (128, 1024) fp32
  unsigned int* wsmax = (unsigned int*)d_ws;
  float* partial = (float*)((char*)d_ws + 256);

  const size_t need32 = 256 + (size_t)32 * 131072 * sizeof(float);  // 16.8 MB
  const size_t need16 = 256 + (size_t)16 * 131072 * sizeof(float);  //  8.4 MB

  hipMemsetAsync(wsmax, 0, 4, stream);
  maxabs_kernel<<<256, 256, 0, stream>>>(w, b, wsmax);

  if (ws_size >= need32) {
    dim3 grid(16, 32);
    memristor_kernel<32, true><<<grid, 256, 0, stream>>>(x, w, b, wsmax, partial);
    reduce_kernel<32><<<128, 256, 0, stream>>>(partial, wsmax, out);
  } else if (ws_size >= need16) {
    dim3 grid(16, 16);
    memristor_kernel<16, true><<<grid, 256, 0, stream>>>(x, w, b, wsmax, partial);
    reduce_kernel<16><<<128, 256, 0, stream>>>(partial, wsmax, out);
  } else {
    hipMemsetAsync(out, 0, (size_t)out_size * sizeof(float), stream);
    dim3 grid(16, 16);
    memristor_kernel<16, false><<<grid, 256, 0, stream>>>(x, w, b, wsmax, out);
  }
}

// Round 6
// 47.904 us; speedup vs baseline: 2.3466x; 1.0071x over previous
//
#include <hip/hip_runtime.h>
#include <cstdint>

#define K_V_C   1.05f
#define G_DIFF  4.0e-4f   // G_MAX - G_MIN
#define KPAD    3168      // 3 levels * 1056 padded j  (= 32 * 99)
#define KSTEPS  99

typedef __attribute__((ext_vector_type(8))) short short8;
typedef __attribute__((ext_vector_type(4))) float f32x4;

// I_REF rows 1..3 (row 0 is all zeros)
__device__ __constant__ float c_I1[9] = {-0.00015f,-0.00011f,-7e-05f,-3e-05f,0.f,3e-05f,7e-05f,0.00011f,0.00015f};
__device__ __constant__ float c_I2[9] = {-0.0005f,-0.00035f,-0.00022f,-9e-05f,0.f,9e-05f,0.00022f,0.00035f,0.0005f};
__device__ __constant__ float c_I3[9] = {-0.0009f,-0.0006f,-0.00037f,-0.00015f,0.f,0.00015f,0.00037f,0.0006f,0.0009f};

__device__ inline unsigned short f2bf(float f) {   // fp32 -> bf16 RNE
  unsigned int u = __float_as_uint(f);
  u += 0x7FFFu + ((u >> 16) & 1u);
  return (unsigned short)(u >> 16);
}

// 3 level currents at voltage v (piecewise-linear interp of I_REF rows 1..3)
__device__ inline void interp3(float v, float& u1, float& u2, float& u3) {
  const float sf = v * 3.3333333333333335f + 4.0f;   // (v+1.2)/0.3
  float fs = floorf(sf);
  fs = fminf(fmaxf(fs, 0.f), 7.f);
  const int   s  = (int)fs;
  const float fr = fminf(fmaxf(sf - fs, 0.f), 1.f);
  u1 = fmaf(fr, c_I1[s+1] - c_I1[s], c_I1[s]);
  u2 = fmaf(fr, c_I2[s+1] - c_I2[s], c_I2[s]);
  u3 = fmaf(fr, c_I3[s+1] - c_I3[s], c_I3[s]);
}

// per-weight level coefficients (searchsorted(right)-1 on G_REF, sign, lerp t)
__device__ inline void coeff3(float g, float& c1, float& c2, float& c3) {
  const float ga  = fabsf(g);
  const float sgn = (g > 0.f) ? 1.f : ((g < 0.f) ? -1.f : 0.f);
  const int   idx = (ga >= 3e-4f) ? 2 : ((ga >= 1e-4f) ? 1 : 0);
  const float g0   = (idx == 0) ? 0.f : ((idx == 1) ? 1e-4f : 3e-4f);
  const float invd = (idx == 0) ? 1e4f : 5e3f;
  const float t    = (ga - g0) * invd;
  const float clo = sgn * (1.f - t), chi = sgn * t;
  c1 = (idx == 0) ? chi : ((idx == 1) ? clo : 0.f);
  c2 = (idx == 1) ? chi : ((idx == 2) ? clo : 0.f);
  c3 = (idx == 2) ? chi : 0.f;
}

// ---------------------------------------------------------------------------
// Kernel 1: max(|w|, |b|) reduction -> ws[0] (float bits in uint, atomicMax)
// ---------------------------------------------------------------------------
__global__ __launch_bounds__(256) void maxabs_kernel(const float* __restrict__ w,
                                                     const float* __restrict__ b,
                                                     unsigned int* __restrict__ wsmax) {
  const int NW4 = 262144, NB4 = 256;
  float m = 0.f;
  for (int i = blockIdx.x * blockDim.x + threadIdx.x; i < NW4 + NB4;
       i += gridDim.x * blockDim.x) {
    float4 v = (i < NW4) ? ((const float4*)w)[i] : ((const float4*)b)[i - NW4];
    m = fmaxf(m, fmaxf(fmaxf(fabsf(v.x), fabsf(v.y)),
                       fmaxf(fabsf(v.z), fabsf(v.w))));
  }
  for (int o = 32; o > 0; o >>= 1) m = fmaxf(m, __shfl_down(m, o, 64));
  __shared__ float red[4];
  const int lane = threadIdx.x & 63, wv = threadIdx.x >> 6;
  if (lane == 0) red[wv] = m;
  __syncthreads();
  if (threadIdx.x == 0) {
    m = fmaxf(fmaxf(red[0], red[1]), fmaxf(red[2], red[3]));
    atomicMax(wsmax, __float_as_uint(m));
  }
}

// ---------------------------------------------------------------------------
// Kernel 2: prep U bf16 [128][KPAD], k = 3*j + level. 132 blocks x 256.
// ---------------------------------------------------------------------------
__global__ __launch_bounds__(256) void prepU_kernel(const float* __restrict__ x,
                                                    unsigned short* __restrict__ Ub) {
  const int idx = blockIdx.x * 256 + threadIdx.x;   // 33792 = 128 * 264
  const int b = idx / 264, j4 = idx - b * 264;
  unsigned short h[12];
  #pragma unroll
  for (int jj = 0; jj < 4; ++jj) {
    const int j = j4 * 4 + jj;
    float u1 = 0.f, u2 = 0.f, u3 = 0.f;
    if (j <= 1024) {
      const float v = (j < 1024) ? K_V_C * x[b * 1024 + j] : K_V_C;
      interp3(v, u1, u2, u3);
    }
    h[jj*3+0] = f2bf(u1); h[jj*3+1] = f2bf(u2); h[jj*3+2] = f2bf(u3);
  }
  ushort4* dst = (ushort4*)(Ub + (size_t)b * KPAD + j4 * 12);
  dst[0] = make_ushort4(h[0], h[1], h[2],  h[3]);
  dst[1] = make_ushort4(h[4], h[5], h[6],  h[7]);
  dst[2] = make_ushort4(h[8], h[9], h[10], h[11]);
}

// ---------------------------------------------------------------------------
// Kernel 3: prep C^T bf16 [1024 m][KPAD], k = 3*j + level.
//   grid (4 m-tiles of 256, 33 j-tiles of 32), block 256.
//   LDS-transpose w tile so global reads AND writes stay coalesced.
// ---------------------------------------------------------------------------
__global__ __launch_bounds__(256) void prepC_kernel(const float* __restrict__ w,
                                                    const float* __restrict__ bias,
                                                    const unsigned int* __restrict__ wsmax,
                                                    unsigned short* __restrict__ Cb) {
  __shared__ float wt[32][260];
  const int t  = threadIdx.x;
  const int m0 = blockIdx.x * 256, j0 = blockIdx.y * 32;
  #pragma unroll
  for (int s = 0; s < 8; ++s) {
    const int r = s * 4 + (t >> 6);
    const int c = (t & 63) * 4;
    const int j = j0 + r;
    float4 v = make_float4(0.f, 0.f, 0.f, 0.f);
    if (j < 1024)       v = *(const float4*)(w + j * 1024 + m0 + c);
    else if (j == 1024) v = *(const float4*)(bias + m0 + c);
    *(float4*)&wt[r][c] = v;
  }
  __syncthreads();
  const float kG = G_DIFF / __uint_as_float(*wsmax);
  const int m = m0 + t;
  unsigned short* dst = Cb + (size_t)m * KPAD + j0 * 3;
  #pragma unroll
  for (int g = 0; g < 8; ++g) {
    unsigned short h[12];
    #pragma unroll
    for (int jj = 0; jj < 4; ++jj) {
      float c1, c2, c3;
      coeff3(kG * wt[g * 4 + jj][t], c1, c2, c3);
      h[jj*3+0] = f2bf(c1); h[jj*3+1] = f2bf(c2); h[jj*3+2] = f2bf(c3);
    }
    ushort4* d4 = (ushort4*)(dst + g * 12);
    d4[0] = make_ushort4(h[0], h[1], h[2],  h[3]);
    d4[1] = make_ushort4(h[4], h[5], h[6],  h[7]);
    d4[2] = make_ushort4(h[8], h[9], h[10], h[11]);
  }
}

// ---------------------------------------------------------------------------
// Kernel 4: GEMM y[b][m] = scale * sum_k U[b][k] * C^T[m][k] via
//   mfma_f32_16x16x32_bf16. 256 blocks x 128 thr (2 waves); one 16x16
//   output tile per wave; K = KPAD in 99 steps; frags loaded from global.
// ---------------------------------------------------------------------------
__global__ __launch_bounds__(128) void gemm_kernel(
    const unsigned short* __restrict__ Ub, const unsigned short* __restrict__ Cb,
    const unsigned int* __restrict__ wsmax, float* __restrict__ out) {
  const int t    = threadIdx.x;
  const int tile = blockIdx.x * 2 + (t >> 6);   // 0..511 = 8 b-tiles x 64 n-tiles
  const int b0   = (tile >> 6) * 16;
  const int n0   = (tile & 63) * 16;
  const int lane = t & 63, la = lane & 15, kg = lane >> 4;

  const unsigned short* Ap = Ub + (size_t)(b0 + la) * KPAD + kg * 8;
  const unsigned short* Bp = Cb + (size_t)(n0 + la) * KPAD + kg * 8;

  f32x4 acc = {0.f, 0.f, 0.f, 0.f};
  #pragma unroll 3
  for (int ks = 0; ks < KSTEPS; ++ks) {
    const short8 a = *(const short8*)(Ap + ks * 32);
    const short8 b = *(const short8*)(Bp + ks * 32);
    acc = __builtin_amdgcn_mfma_f32_16x16x32_bf16(a, b, acc, 0, 0, 0);
  }

  const float scale = __uint_as_float(*wsmax) * (1.0f / (K_V_C * G_DIFF));
  const int brow = b0 + kg * 4;
  #pragma unroll
  for (int r = 0; r < 4; ++r)
    out[(size_t)(brow + r) * 1024 + n0 + la] = acc[r] * scale;   // D: col=lane&15, row=kg*4+r
}

// ---------------------------------------------------------------------------
// Fallback (tiny ws): fused VALU kernel with atomicAdd epilogue (round-2 form).
// ---------------------------------------------------------------------------
__global__ __launch_bounds__(256) void memristor_atomic_kernel(
    const float* __restrict__ x, const float* __restrict__ w,
    const float* __restrict__ bias, const unsigned int* __restrict__ wsmax,
    float* __restrict__ out) {
  __shared__ float4 U[2048];
  const int tid = threadIdx.x;
  const float maxw  = __uint_as_float(*wsmax);
  const float kG    = G_DIFF / maxw;
  const float scale = maxw * (1.0f / (K_V_C * G_DIFF));
  const int mq = tid & 15, bg = tid >> 4;
  const int m0 = blockIdx.x * 64 + mq * 4;
  const int swz = bg & 7;
  float acc[4][8];
  #pragma unroll
  for (int a = 0; a < 4; ++a)
    #pragma unroll
    for (int c = 0; c < 8; ++c) acc[a][c] = 0.f;
  for (int sc = blockIdx.y; sc < 65; sc += 16) {
    const int j0 = sc * 16;
    const int nj = min(16, 1025 - j0);
    __syncthreads();
    #pragma unroll
    for (int k = 0; k < 8; ++k) {
      const int e = k * 256 + tid;
      const int jl = e & 15, b = e >> 4;
      const int jg = j0 + jl;
      if (jg <= 1024) {
        const float v = (jg < 1024) ? K_V_C * x[b * 1024 + jg] : K_V_C;
        float u1, u2, u3;
        interp3(v, u1, u2, u3);
        U[b * 16 + (jl ^ ((b >> 3) & 7))] = make_float4(0.f, u1, u2, u3);
      }
    }
    __syncthreads();
    for (int jl = 0; jl < nj; ++jl) {
      const int jg = j0 + jl;
      const float4 wv = (jg < 1024) ? *(const float4*)(w + jg * 1024 + m0)
                                    : *(const float4*)(bias + m0);
      const float warr[4] = {wv.x, wv.y, wv.z, wv.w};
      float c1[4], c2[4], c3[4];
      #pragma unroll
      for (int mi = 0; mi < 4; ++mi) coeff3(kG * warr[mi], c1[mi], c2[mi], c3[mi]);
      const int base = bg * 128 + (jl ^ swz);
      #pragma unroll
      for (int bb = 0; bb < 8; ++bb) {
        const float4 u = U[base + bb * 16];
        #pragma unroll
        for (int mi = 0; mi < 4; ++mi)
          acc[mi][bb] = fmaf(c1[mi], u.y, fmaf(c2[mi], u.z, fmaf(c3[mi], u.w, acc[mi][bb])));
      }
    }
  }
  #pragma unroll
  for (int bb = 0; bb < 8; ++bb) {
    const int b = bg * 8 + bb;
    #pragma unroll
    for (int mi = 0; mi < 4; ++mi)
      atomicAdd(&out[b * 1024 + m0 + mi], acc[mi][bb] * scale);
  }
}

// ---------------------------------------------------------------------------
extern "C" void kernel_launch(void* const* d_in, const int* in_sizes, int n_in,
                              void* d_out, int out_size, void* d_ws, size_t ws_size,
                              hipStream_t stream) {
  const float* x = (const float*)d_in[0];   // (128, 1024)
  const float* w = (const float*)d_in[1];   // (1024, 1024)
  const float* b = (const float*)d_in[2];   // (1024,)
  float* out = (float*)d_out;               // (128, 1024) fp32
  unsigned int*   wsmax = (unsigned int*)d_ws;
  unsigned short* Ub = (unsigned short*)((char*)d_ws + 1024);           // 811,008 B
  unsigned short* Cb = (unsigned short*)((char*)d_ws + (1u << 20));     // 6,488,064 B

  const size_t need = (1u << 20) + (size_t)1024 * KPAD * 2;             // ~7.5 MB

  hipMemsetAsync(wsmax, 0, 4, stream);
  maxabs_kernel<<<256, 256, 0, stream>>>(w, b, wsmax);

  if (ws_size >= need) {
    prepU_kernel<<<132, 256, 0, stream>>>(x, Ub);
    prepC_kernel<<<dim3(4, 33), 256, 0, stream>>>(w, b, wsmax, Cb);
    gemm_kernel<<<256, 128, 0, stream>>>(Ub, Cb, wsmax, out);
  } else {
    hipMemsetAsync(out, 0, (size_t)out_size * sizeof(float), stream);
    dim3 grid(16, 16);
    memristor_atomic_kernel<<<grid, 256, 0, stream>>>(x, w, b, wsmax, out);
  }
}

// Round 7
// 32.116 us; speedup vs baseline: 3.5002x; 1.4916x over previous
//
#include <hip/hip_runtime.h>
#include <cstdint>

#define K_V_C   1.05f
#define G_DIFF  4.0e-4f   // G_MAX - G_MIN
#define KPAD    3456      // k = 3*j + level, j padded to 1152; = 12*288 = 32*108
#define NSTEP   27        // MFMA K-steps per k-slice (4 slices of 864)

typedef __attribute__((ext_vector_type(8))) short short8;
typedef __attribute__((ext_vector_type(4))) float f32x4;

// I_REF rows 1..3 (row 0 is all zeros)
__device__ __constant__ float c_I1[9] = {-0.00015f,-0.00011f,-7e-05f,-3e-05f,0.f,3e-05f,7e-05f,0.00011f,0.00015f};
__device__ __constant__ float c_I2[9] = {-0.0005f,-0.00035f,-0.00022f,-9e-05f,0.f,9e-05f,0.00022f,0.00035f,0.0005f};
__device__ __constant__ float c_I3[9] = {-0.0009f,-0.0006f,-0.00037f,-0.00015f,0.f,0.00015f,0.00037f,0.0006f,0.0009f};

__device__ inline unsigned short f2bf(float f) {   // fp32 -> bf16 RNE
  unsigned int u = __float_as_uint(f);
  u += 0x7FFFu + ((u >> 16) & 1u);
  return (unsigned short)(u >> 16);
}

__device__ inline void interp3(float v, float& u1, float& u2, float& u3) {
  const float sf = v * 3.3333333333333335f + 4.0f;   // (v+1.2)/0.3
  float fs = floorf(sf);
  fs = fminf(fmaxf(fs, 0.f), 7.f);
  const int   s  = (int)fs;
  const float fr = fminf(fmaxf(sf - fs, 0.f), 1.f);
  u1 = fmaf(fr, c_I1[s+1] - c_I1[s], c_I1[s]);
  u2 = fmaf(fr, c_I2[s+1] - c_I2[s], c_I2[s]);
  u3 = fmaf(fr, c_I3[s+1] - c_I3[s], c_I3[s]);
}

__device__ inline void coeff3(float g, float& c1, float& c2, float& c3) {
  const float ga  = fabsf(g);
  const float sgn = (g > 0.f) ? 1.f : ((g < 0.f) ? -1.f : 0.f);
  const int   idx = (ga >= 3e-4f) ? 2 : ((ga >= 1e-4f) ? 1 : 0);
  const float g0   = (idx == 0) ? 0.f : ((idx == 1) ? 1e-4f : 3e-4f);
  const float invd = (idx == 0) ? 1e4f : 5e3f;
  const float t    = (ga - g0) * invd;
  const float clo = sgn * (1.f - t), chi = sgn * t;
  c1 = (idx == 0) ? chi : ((idx == 1) ? clo : 0.f);
  c2 = (idx == 1) ? chi : ((idx == 2) ? clo : 0.f);
  c3 = (idx == 2) ? chi : 0.f;
}

// all-lane max of the 1024 block-partials (each lane loads float4, butterfly)
__device__ inline float partials_max(const float* __restrict__ partials, int t) {
  const float4 pv = ((const float4*)partials)[t & 63];
  float m = fmaxf(fmaxf(pv.x, pv.y), fmaxf(pv.z, pv.w));
  #pragma unroll
  for (int o = 1; o < 64; o <<= 1) m = fmaxf(m, __shfl_xor(m, o, 64));
  return m;
}

// ---------------------------------------------------------------------------
// Kernel 1: per-block max(|w|,|b|) partials -> partials[1024]. No atomics.
//   1024 blocks x 256 thr: exactly one float4 per thread (+bias on first 256).
// ---------------------------------------------------------------------------
__global__ __launch_bounds__(256) void maxabs_kernel(const float* __restrict__ w,
                                                     const float* __restrict__ b,
                                                     float* __restrict__ partials) {
  const int i = blockIdx.x * 256 + threadIdx.x;     // 0..262143 over w as float4
  float4 v = ((const float4*)w)[i];
  float m = fmaxf(fmaxf(fabsf(v.x), fabsf(v.y)), fmaxf(fabsf(v.z), fabsf(v.w)));
  if (i < 256) {
    float4 bv = ((const float4*)b)[i];
    m = fmaxf(m, fmaxf(fmaxf(fabsf(bv.x), fabsf(bv.y)),
                       fmaxf(fabsf(bv.z), fabsf(bv.w))));
  }
  #pragma unroll
  for (int o = 32; o > 0; o >>= 1) m = fmaxf(m, __shfl_down(m, o, 64));
  __shared__ float red[4];
  if ((threadIdx.x & 63) == 0) red[threadIdx.x >> 6] = m;
  __syncthreads();
  if (threadIdx.x == 0)
    partials[blockIdx.x] = fmaxf(fmaxf(red[0], red[1]), fmaxf(red[2], red[3]));
}

// ---------------------------------------------------------------------------
// Kernel 2: fused prep. blocks 0..143: U bf16 [128][KPAD] from x.
//           blocks 144..287: C^T bf16 [1024][KPAD] from w/bias (LDS transpose).
//   k = 3*j + level; j >= 1025 zero-padded.
// ---------------------------------------------------------------------------
__global__ __launch_bounds__(256) void prep_kernel(
    const float* __restrict__ x, const float* __restrict__ w,
    const float* __restrict__ bias, const float* __restrict__ partials,
    unsigned short* __restrict__ Ub, unsigned short* __restrict__ Cb) {
  __shared__ float wt[32][260];
  const int bid = blockIdx.x, t = threadIdx.x;

  if (bid < 144) {                       // ---- U part ----
    const int idx = bid * 256 + t;       // 36864 = 128 b x 288 j4-groups
    const int b = idx / 288, j4 = idx - b * 288;
    unsigned short h[12];
    if (j4 < 256) {
      const float4 xv = *(const float4*)(x + b * 1024 + j4 * 4);
      const float vx[4] = {xv.x, xv.y, xv.z, xv.w};
      #pragma unroll
      for (int jj = 0; jj < 4; ++jj) {
        float u1, u2, u3;
        interp3(K_V_C * vx[jj], u1, u2, u3);
        h[jj*3] = f2bf(u1); h[jj*3+1] = f2bf(u2); h[jj*3+2] = f2bf(u3);
      }
    } else {
      #pragma unroll
      for (int i = 0; i < 12; ++i) h[i] = 0;
      if (j4 == 256) {                   // j = 1024: the ones/bias column
        float u1, u2, u3;
        interp3(K_V_C, u1, u2, u3);
        h[0] = f2bf(u1); h[1] = f2bf(u2); h[2] = f2bf(u3);
      }
    }
    ushort4* dst = (ushort4*)(Ub + (size_t)b * KPAD + j4 * 12);
    dst[0] = make_ushort4(h[0], h[1], h[2],  h[3]);
    dst[1] = make_ushort4(h[4], h[5], h[6],  h[7]);
    dst[2] = make_ushort4(h[8], h[9], h[10], h[11]);
  } else {                               // ---- C part ----
    const int cid = bid - 144;
    const int m0 = (cid & 3) * 256, j0 = (cid >> 2) * 32;   // 36 j-tiles
    #pragma unroll
    for (int s = 0; s < 8; ++s) {
      const int r = s * 4 + (t >> 6);
      const int c = (t & 63) * 4;
      const int j = j0 + r;
      float4 v = make_float4(0.f, 0.f, 0.f, 0.f);
      if (j < 1024)       v = *(const float4*)(w + j * 1024 + m0 + c);
      else if (j == 1024) v = *(const float4*)(bias + m0 + c);
      *(float4*)&wt[r][c] = v;
    }
    const float kG = G_DIFF / partials_max(partials, t);
    __syncthreads();
    const int m = m0 + t;
    unsigned short* dst = Cb + (size_t)m * KPAD + j0 * 3;
    #pragma unroll
    for (int g = 0; g < 8; ++g) {
      unsigned short h[12];
      #pragma unroll
      for (int jj = 0; jj < 4; ++jj) {
        float c1, c2, c3;
        coeff3(kG * wt[g * 4 + jj][t], c1, c2, c3);
        h[jj*3] = f2bf(c1); h[jj*3+1] = f2bf(c2); h[jj*3+2] = f2bf(c3);
      }
      ushort4* d4 = (ushort4*)(dst + g * 12);
      d4[0] = make_ushort4(h[0], h[1], h[2],  h[3]);
      d4[1] = make_ushort4(h[4], h[5], h[6],  h[7]);
      d4[2] = make_ushort4(h[8], h[9], h[10], h[11]);
    }
  }
}

// ---------------------------------------------------------------------------
// Kernel 3: GEMM y = scale * U . C^T via mfma_f32_16x16x32_bf16, split-K x4.
//   512 blocks (one 16x16 tile each) x 4 waves (one k-slice each);
//   9-deep load groups; LDS cross-wave K-reduction; fused scale epilogue.
// ---------------------------------------------------------------------------
__global__ __launch_bounds__(256, 2) void gemm_kernel(
    const unsigned short* __restrict__ Ub, const unsigned short* __restrict__ Cb,
    const float* __restrict__ partials, float* __restrict__ out) {
  __shared__ float P[4][256];
  const int t = threadIdx.x;
  const int wv = t >> 6;                 // wave = k-slice 0..3
  const int lane = t & 63, la = lane & 15, kg = lane >> 4;
  const int tile = blockIdx.x;           // 8 b-tiles x 64 n-tiles
  const int b0 = (tile >> 6) * 16;
  const int n0 = (tile & 63) * 16;

  const size_t kbase = (size_t)wv * 864 + kg * 8;
  const unsigned short* Ap = Ub + (size_t)(b0 + la) * KPAD + kbase;
  const unsigned short* Bp = Cb + (size_t)(n0 + la) * KPAD + kbase;

  f32x4 acc = {0.f, 0.f, 0.f, 0.f};
  #pragma unroll
  for (int g = 0; g < 3; ++g) {          // 27 steps = 3 groups of 9 in flight
    short8 a[9], b[9];
    #pragma unroll
    for (int i = 0; i < 9; ++i) {
      a[i] = *(const short8*)(Ap + (g * 9 + i) * 32);
      b[i] = *(const short8*)(Bp + (g * 9 + i) * 32);
    }
    #pragma unroll
    for (int i = 0; i < 9; ++i)
      acc = __builtin_amdgcn_mfma_f32_16x16x32_bf16(a[i], b[i], acc, 0, 0, 0);
  }

  *(float4*)&P[wv][lane * 4] = make_float4(acc[0], acc[1], acc[2], acc[3]);
  const float scale = partials_max(partials, t) * (1.0f / (K_V_C * G_DIFF));
  __syncthreads();

  const int l2 = t & 63, ai = t >> 6;
  const float s = P[0][l2*4+ai] + P[1][l2*4+ai] + P[2][l2*4+ai] + P[3][l2*4+ai];
  const int row = b0 + (l2 >> 4) * 4 + ai;     // D: col = lane&15, row = kg*4+r
  const int col = n0 + (l2 & 15);
  out[(size_t)row * 1024 + col] = s * scale;
}

// ---------------------------------------------------------------------------
// Fallback path (tiny ws): atomic-based, needs only 4 bytes of ws.
// ---------------------------------------------------------------------------
__global__ __launch_bounds__(256) void maxabs_atomic_kernel(
    const float* __restrict__ w, const float* __restrict__ b,
    unsigned int* __restrict__ wsmax) {
  const int NW4 = 262144, NB4 = 256;
  float m = 0.f;
  for (int i = blockIdx.x * blockDim.x + threadIdx.x; i < NW4 + NB4;
       i += gridDim.x * blockDim.x) {
    float4 v = (i < NW4) ? ((const float4*)w)[i] : ((const float4*)b)[i - NW4];
    m = fmaxf(m, fmaxf(fmaxf(fabsf(v.x), fabsf(v.y)),
                       fmaxf(fabsf(v.z), fabsf(v.w))));
  }
  #pragma unroll
  for (int o = 32; o > 0; o >>= 1) m = fmaxf(m, __shfl_down(m, o, 64));
  __shared__ float red[4];
  if ((threadIdx.x & 63) == 0) red[threadIdx.x >> 6] = m;
  __syncthreads();
  if (threadIdx.x == 0)
    atomicMax(wsmax, __float_as_uint(fmaxf(fmaxf(red[0], red[1]),
                                           fmaxf(red[2], red[3]))));
}

__global__ __launch_bounds__(256) void memristor_atomic_kernel(
    const float* __restrict__ x, const float* __restrict__ w,
    const float* __restrict__ bias, const unsigned int* __restrict__ wsmax,
    float* __restrict__ out) {
  __shared__ float4 U[2048];
  const int tid = threadIdx.x;
  const float maxw  = __uint_as_float(*wsmax);
  const float kG    = G_DIFF / maxw;
  const float scale = maxw * (1.0f / (K_V_C * G_DIFF));
  const int mq = tid & 15, bg = tid >> 4;
  const int m0 = blockIdx.x * 64 + mq * 4;
  const int swz = bg & 7;
  float acc[4][8];
  #pragma unroll
  for (int a = 0; a < 4; ++a)
    #pragma unroll
    for (int c = 0; c < 8; ++c) acc[a][c] = 0.f;
  for (int sc = blockIdx.y; sc < 65; sc += 16) {
    const int j0 = sc * 16;
    const int nj = min(16, 1025 - j0);
    __syncthreads();
    #pragma unroll
    for (int k = 0; k < 8; ++k) {
      const int e = k * 256 + tid;
      const int jl = e & 15, b = e >> 4;
      const int jg = j0 + jl;
      if (jg <= 1024) {
        const float v = (jg < 1024) ? K_V_C * x[b * 1024 + jg] : K_V_C;
        float u1, u2, u3;
        interp3(v, u1, u2, u3);
        U[b * 16 + (jl ^ ((b >> 3) & 7))] = make_float4(0.f, u1, u2, u3);
      }
    }
    __syncthreads();
    for (int jl = 0; jl < nj; ++jl) {
      const int jg = j0 + jl;
      const float4 wv = (jg < 1024) ? *(const float4*)(w + jg * 1024 + m0)
                                    : *(const float4*)(bias + m0);
      const float warr[4] = {wv.x, wv.y, wv.z, wv.w};
      float c1[4], c2[4], c3[4];
      #pragma unroll
      for (int mi = 0; mi < 4; ++mi) coeff3(kG * warr[mi], c1[mi], c2[mi], c3[mi]);
      const int base = bg * 128 + (jl ^ swz);
      #pragma unroll
      for (int bb = 0; bb < 8; ++bb) {
        const float4 u = U[base + bb * 16];
        #pragma unroll
        for (int mi = 0; mi < 4; ++mi)
          acc[mi][bb] = fmaf(c1[mi], u.y, fmaf(c2[mi], u.z, fmaf(c3[mi], u.w, acc[mi][bb])));
      }
    }
  }
  #pragma unroll
  for (int bb = 0; bb < 8; ++bb) {
    const int b = bg * 8 + bb;
    #pragma unroll
    for (int mi = 0; mi < 4; ++mi)
      atomicAdd(&out[b * 1024 + m0 + mi], acc[mi][bb] * scale);
  }
}

// ---------------------------------------------------------------------------
extern "C" void kernel_launch(void* const* d_in, const int* in_sizes, int n_in,
                              void* d_out, int out_size, void* d_ws, size_t ws_size,
                              hipStream_t stream) {
  const float* x = (const float*)d_in[0];   // (128, 1024)
  const float* w = (const float*)d_in[1];   // (1024, 1024)
  const float* b = (const float*)d_in[2];   // (1024,)
  float* out = (float*)d_out;               // (128, 1024) fp32

  float*          partials = (float*)((char*)d_ws + 128);               // 1024 f32
  unsigned short* Ub = (unsigned short*)((char*)d_ws + 8192);           // 884,736 B
  unsigned short* Cb = (unsigned short*)((char*)d_ws + (1u << 20));     // 7,077,888 B
  const size_t need = (1u << 20) + (size_t)1024 * KPAD * 2;             // ~8.1 MB

  if (ws_size >= need) {
    maxabs_kernel<<<1024, 256, 0, stream>>>(w, b, partials);
    prep_kernel<<<288, 256, 0, stream>>>(x, w, b, partials, Ub, Cb);
    gemm_kernel<<<512, 256, 0, stream>>>(Ub, Cb, partials, out);
  } else {
    unsigned int* wsmax = (unsigned int*)d_ws;
    hipMemsetAsync(wsmax, 0, 4, stream);
    maxabs_atomic_kernel<<<256, 256, 0, stream>>>(w, b, wsmax);
    hipMemsetAsync(out, 0, (size_t)out_size * sizeof(float), stream);
    dim3 grid(16, 16);
    memristor_atomic_kernel<<<grid, 256, 0, stream>>>(x, w, b, wsmax, out);
  }
}